// Round 4
// baseline (160.224 us; speedup 1.0000x reference)
//
#include <hip/hip_runtime.h>
#include <hip/hip_bf16.h>

#define B_ 2
#define S_ 2048
#define D_ 1024
#define H_ 16
#define HD_ 64

typedef __attribute__((ext_vector_type(8))) short short8;
typedef __attribute__((ext_vector_type(4))) short short4v;
typedef __attribute__((ext_vector_type(4))) float float4v;

typedef const __attribute__((address_space(1))) void* gas_ptr;
typedef __attribute__((address_space(3))) void* las_ptr;

static __device__ inline void gl_lds16(const void* g, void* l) {
  __builtin_amdgcn_global_load_lds((gas_ptr)g, (las_ptr)l, 16, 0, 0);
}

static __device__ inline short f2bs(float x) {
  __hip_bfloat16 h = __float2bfloat16(x);
  union { __hip_bfloat16 h; short s; } u; u.h = h; return u.s;
}
static __device__ inline float bs2f(short s) {
  union { short s; __hip_bfloat16 h; } u; u.s = s; return __bfloat162float(u.h);
}
// packed f32x4 -> bf16x4 (v_cvt_pk_bf16_f32 x2)
static __device__ inline short4v pk4(float a, float b, float c, float d) {
  union { __hip_bfloat162 h[2]; short4v s; } u;
  u.h[0] = __float22bfloat162_rn(float2{a, b});
  u.h[1] = __float22bfloat162_rn(float2{c, d});
  return u.s;
}

static __device__ inline float4v mfma32(short8 a, short8 b, float4v c) {
  return __builtin_amdgcn_mfma_f32_16x16x32_bf16(a, b, c, 0, 0, 0);
}
// v_mfma_f32_16x16x16_bf16 — "_1k" builtin, present on gfx950.
static __device__ inline float4v mfma16(short4v a, short4v b, float4v c) {
  return __builtin_amdgcn_mfma_f32_16x16x16bf16_1k(a, b, c, 0, 0, 0);
}

// ------- Stage A (merged): blocks [0,2048): hs fp32->bf16; blocks [2048,2560):
// W fp32 [k][n] -> Wt bf16 [n][k]. -------
__global__ __launch_bounds__(256) void prep(
    const float* __restrict__ hs, __hip_bfloat16* __restrict__ hsb,
    const float* __restrict__ Wq, const float* __restrict__ Wk,
    __hip_bfloat16* __restrict__ Wqt, __hip_bfloat16* __restrict__ Wkt) {
  __shared__ float t[64][65];
  const int id = blockIdx.x;
  if (id < 2048) {
    const size_t i = ((size_t)id * 256 + threadIdx.x) * 8;
    const float4v a0 = ((const float4v*)(hs + i))[0];
    const float4v a1 = ((const float4v*)(hs + i))[1];
    short8 s;
#pragma unroll
    for (int j = 0; j < 4; ++j) { s[j] = f2bs(a0[j]); s[4 + j] = f2bs(a1[j]); }
    *(short8*)(hsb + i) = s;
    return;
  }
  const int bid = id - 2048;
  const float* W = (bid >> 8) ? Wk : Wq;
  __hip_bfloat16* Wt = (bid >> 8) ? Wkt : Wqt;
  const int n0 = (bid & 15) * 64, k0 = ((bid >> 4) & 15) * 64;
  const int c = threadIdx.x & 63, r0 = threadIdx.x >> 6;
  for (int i = 0; i < 16; ++i) {
    const int r = i * 4 + r0;
    t[c][r] = W[(size_t)(k0 + r) * D_ + n0 + c];
  }
  __syncthreads();
  for (int i = 0; i < 16; ++i) {
    const int rr = i * 4 + r0;
    Wt[(size_t)(n0 + rr) * D_ + k0 + c] = __float2bfloat16(t[rr][c]);
  }
}

// ---- Stage B (fused GEMM+prep): 64x128 tile, 4 waves, 2 blocks/CU.
// r19: BK=64 — one barrier pair per 64-K (was 32-K). Same total gl_lds /
// ds_read / mfma; barrier count halved. Occupancy pinned by grid (512=2/CU)
// so the 80KB LDS costs nothing (m132's BK-regression was occupancy loss).
// 64-wide rows: 3-bit chunk XOR swizzle c^(row&7), pre-swizzled global
// source (rule #21), de-swizzled on ds_read -> conflict-free b128.
__global__ __launch_bounds__(256, 2) void gemm_fused(
    const __hip_bfloat16* __restrict__ hsb,
    const __hip_bfloat16* __restrict__ Wqt, const __hip_bfloat16* __restrict__ Wkt,
    const float* __restrict__ bq, const float* __restrict__ bk,
    __hip_bfloat16* __restrict__ q_out, __hip_bfloat16* __restrict__ kt_out,
    __hip_bfloat16* __restrict__ vT) {
  const int id = blockIdx.x;
  const int mt = (id & 7) * 8 + ((id >> 3) & 7);  // m-tile 0..63, pinned by xcd
  const int nt = id >> 6;                          // n-block 0..7
  const int n0 = nt * 128, m0 = mt * 64;
  __shared__ __hip_bfloat16 As[2][64 * 64];    // 16KB
  __shared__ __hip_bfloat16 Bq[2][128 * 64];   // 32KB
  __shared__ __hip_bfloat16 Bk[2][128 * 64];   // 32KB
  const int tid = threadIdx.x, wid = tid >> 6, lane = tid & 63;
  const int wm = (wid >> 1) * 32, wn = (wid & 1) * 64;
  const int l15 = lane & 15, l4 = lane >> 4;
  const float4v zz = {0.f, 0.f, 0.f, 0.f};
  float4v accq[2][4], acck[2][4];
  for (int i = 0; i < 2; ++i)
    for (int j = 0; j < 4; ++j) { accq[i][j] = zz; acck[i][j] = zz; }
  // staging: each gl_lds16 inst covers 8 rows x 64 cols (64 lanes x 16B).
  // lane -> row (lane>>3), chunk (lane&7); source chunk pre-swizzled
  // g = (lane&7) ^ (row&7) so LDS row r holds chunk c at slot c^(r&7).
  const int srow8 = lane >> 3;
  const int schunk = ((lane & 7) ^ (srow8 & 7)) * 8;  // shorts
  const int arow = wid * 16 + srow8;   // + j*8
  const int brow = wid * 32 + srow8;   // + j*8
#define STAGE(pp, kc)                                                          \
  {                                                                            \
    _Pragma("unroll")                                                          \
    for (int j = 0; j < 2; ++j)                                                \
      gl_lds16(hsb + (size_t)(m0 + arow + j * 8) * D_ + (kc) + schunk,         \
               As[pp] + wid * 1024 + j * 512);                                 \
    _Pragma("unroll")                                                          \
    for (int j = 0; j < 4; ++j) {                                              \
      gl_lds16(Wqt + (size_t)(n0 + brow + j * 8) * D_ + (kc) + schunk,         \
               Bq[pp] + wid * 2048 + j * 512);                                 \
      gl_lds16(Wkt + (size_t)(n0 + brow + j * 8) * D_ + (kc) + schunk,         \
               Bk[pp] + wid * 2048 + j * 512);                                 \
    }                                                                          \
  }
  STAGE(0, 0);
  int p = 0;
  for (int kb = 0; kb < 16; ++kb) {
    __syncthreads();  // buf[p] staged (vm drained); prev frag reads done
    if (kb < 15) STAGE(p ^ 1, (kb + 1) * 64);
#pragma unroll
    for (int sub = 0; sub < 2; ++sub) {
      short8 af[2], bfq[4], bfk[4];
      const int fo = ((sub * 4 + l4) ^ (l15 & 7)) * 8;  // de-swizzle on read
#pragma unroll
      for (int rt = 0; rt < 2; ++rt)
        af[rt] = *(const short8*)(As[p] + (wm + rt * 16 + l15) * 64 + fo);
#pragma unroll
      for (int ct = 0; ct < 4; ++ct) {
        bfq[ct] = *(const short8*)(Bq[p] + (wn + ct * 16 + l15) * 64 + fo);
        bfk[ct] = *(const short8*)(Bk[p] + (wn + ct * 16 + l15) * 64 + fo);
      }
#pragma unroll
      for (int rt = 0; rt < 2; ++rt)
#pragma unroll
        for (int ct = 0; ct < 4; ++ct) {
          accq[rt][ct] = mfma32(af[rt], bfq[ct], accq[rt][ct]);
          acck[rt][ct] = mfma32(af[rt], bfk[ct], acck[rt][ct]);
        }
    }
    p ^= 1;
  }
#undef STAGE
  float bvq[4], bvk[4];
  for (int ct = 0; ct < 4; ++ct) {
    bvq[ct] = bq[n0 + wn + ct * 16 + l15];
    bvk[ct] = bk[n0 + wn + ct * 16 + l15];
  }
  for (int rt = 0; rt < 2; ++rt)
    for (int ct = 0; ct < 4; ++ct) {
      const int col = n0 + wn + ct * 16 + l15;
      const int h = col >> 6, d = col & 63;
      const int rowb = m0 + wm + rt * 16 + l4 * 4;
      short4v vv;
      for (int r = 0; r < 4; ++r) {
        const int row = rowb + r;
        const float qv = accq[rt][ct][r] + bvq[ct];
        const float kv = acck[rt][ct][r] + bvk[ct];
        const float sp = fmaxf(kv, 0.f) + __logf(1.f + __expf(-fabsf(kv)));
        q_out[(size_t)row * D_ + col] = __float2bfloat16(qv);
        kt_out[(size_t)row * D_ + col] = __float2bfloat16(sp);
        vv[r] = f2bs(qv + kv);
      }
      const int b = rowb >> 11, s = rowb & 2047;
      // key swizzle p(k) within 64-chunk; s%4==0 -> 4 consecutive stay together
      const int sw = (s & ~63) | (((s >> 4) & 3) << 2) | (((s >> 2) & 3) << 4);
      *(short4v*)(vT + ((size_t)(b * H_ + h) * HD_ + d) * S_ + sw) = vv;
    }
}

// ------- Stage D: flash attention — XCD-pinned, 128-key chunks.
// r19 epilogue fix: the 4194304 SQ_LDS_BANK_CONFLICT (constant across ALL
// main-loop swizzle changes r15-r18) is the epilogue: scalar f32 mbuf writes
// have uniform r per inst -> addrs = r (mod 4) -> only 8/32 banks reachable
// = 8-way conflict x32 insts; reads paired lanes on same row = 2-way.
// Fix: b128 writes (d contiguous in r; banks 4*l15+16dt+4*l4 = full cover)
// and qq=tid&127 reads (64 consecutive lanes -> 64 distinct rows, bank
// 4*lane = full cover). Also: lsum as 4 per-r partials (the += chain was
// 64 serial non-reassociable FP adds per chunk).
__global__ __launch_bounds__(256, 2) void attn(
    const __hip_bfloat16* __restrict__ qb, const __hip_bfloat16* __restrict__ ktb,
    const __hip_bfloat16* __restrict__ vT, const int* __restrict__ mask,
    float* __restrict__ out) {
  // buffer: kt0[4096] kt1[4096] v0[4096] v1[4096] shorts; 2 bufs = 65536 B
  __shared__ short smem[32768];
  const int id = blockIdx.x;
  const int xcd = id & 7;
  const int rest = id >> 3;              // 0..63
  const int q0 = (rest & 15) * 128;      // q-tile
  const int hb = (rest >> 4) * 8 + xcd;  // 0..31
  const int h = hb >> 1, b = hb & 1;
  const int tid = threadIdx.x, wid = tid >> 6, lane = tid & 63;
  const int l15 = lane & 15, l4 = lane >> 4;
  const __hip_bfloat16* qh = qb + (size_t)b * S_ * D_ + h * HD_;
  const __hip_bfloat16* kh = ktb + (size_t)b * S_ * D_ + h * HD_;
  const __hip_bfloat16* vh = vT + (size_t)(b * H_ + h) * HD_ * S_;
  // staging map: row=tid>>2 (0..63), two 16B blocks b0=(tid&3), b0+4
  const int srow = tid >> 2;
  const int b0 = tid & 3;
  const int ssw = ((srow & 1) << 2) | ((srow >> 1) & 3);  // s(row)
  const int w0 = srow * 64 + ((b0 ^ ssw) * 8);
  const int w1 = srow * 64 + (((b0 + 4) ^ ssw) * 8);

  // q B-fragments for tiles A,B; mask*scale*log2e folded in
  const int qlA = wid * 32 + l15, qlB = qlA + 16;
  const int qrA = q0 + qlA, qrB = q0 + qlB;
  const float SC = 0.125f * 1.44269504f;
  const float mqA = (mask[b * S_ + qrA] != 0) ? SC : 0.f;
  const float mqB = (mask[b * S_ + qrB] != 0) ? SC : 0.f;
  const short8 rA0 = *(const short8*)(qh + (size_t)qrA * D_ + l4 * 8);
  const short8 rA1 = *(const short8*)(qh + (size_t)qrA * D_ + 32 + l4 * 8);
  const short8 rB0 = *(const short8*)(qh + (size_t)qrB * D_ + l4 * 8);
  const short8 rB1 = *(const short8*)(qh + (size_t)qrB * D_ + 32 + l4 * 8);
  short8 bqA0, bqA1, bqB0, bqB1;
  for (int j = 0; j < 8; ++j) {
    bqA0[j] = f2bs(bs2f(rA0[j]) * mqA);
    bqA1[j] = f2bs(bs2f(rA1[j]) * mqA);
    bqB0[j] = f2bs(bs2f(rB0[j]) * mqB);
    bqB1[j] = f2bs(bs2f(rB1[j]) * mqB);
  }

  // fragment read offsets (s(row)-swizzled; row&7 == l15&7 for all reads)
  const int lsw = ((l15 & 1) << 2) | ((l15 >> 1) & 3);
  const int ak0off = l15 * 64 + ((l4 ^ lsw) * 8);          // + u*4096 + t*1024
  const int ak1off = l15 * 64 + (((l4 + 4) ^ lsw) * 8);
  const int vb0off = ((2 * l4) ^ lsw) * 8;                 // + 8192 + u*4096 + row*64
  const int vb1off = ((2 * l4 + 1) ^ lsw) * 8;

  const float4v zz = {0.f, 0.f, 0.f, 0.f};
  float4v oaccA[4] = {zz, zz, zz, zz};
  float4v oaccB[4] = {zz, zz, zz, zz};
  float4v lsA = zz, lsB = zz;  // per-r partial sums (4 independent chains)

  // prefetch chunk 0 (two 64-key subchunks)
  short8 gk0[2], gk1[2], gv0[2], gv1[2];
#pragma unroll
  for (int u = 0; u < 2; ++u) {
    gk0[u] = *(const short8*)(kh + (size_t)(u * 64 + srow) * D_ + b0 * 8);
    gk1[u] = *(const short8*)(kh + (size_t)(u * 64 + srow) * D_ + b0 * 8 + 32);
    gv0[u] = *(const short8*)(vh + (size_t)srow * S_ + u * 64 + b0 * 8);
    gv1[u] = *(const short8*)(vh + (size_t)srow * S_ + u * 64 + b0 * 8 + 32);
  }

  int p = 0;
  for (int c = 0; c < 16; ++c) {
    short* bufp = smem + p * 16384;
#pragma unroll
    for (int u = 0; u < 2; ++u) {
      *(short8*)(bufp + u * 4096 + w0) = gk0[u];
      *(short8*)(bufp + u * 4096 + w1) = gk1[u];
      *(short8*)(bufp + 8192 + u * 4096 + w0) = gv0[u];
      *(short8*)(bufp + 8192 + u * 4096 + w1) = gv1[u];
    }
    __syncthreads();
    if (c < 15) {
      const int kb = (c + 1) * 128;
#pragma unroll
      for (int u = 0; u < 2; ++u) {
        gk0[u] = *(const short8*)(kh + (size_t)(kb + u * 64 + srow) * D_ + b0 * 8);
        gk1[u] = *(const short8*)(kh + (size_t)(kb + u * 64 + srow) * D_ + b0 * 8 + 32);
        gv0[u] = *(const short8*)(vh + (size_t)srow * S_ + kb + u * 64 + b0 * 8);
        gv1[u] = *(const short8*)(vh + (size_t)srow * S_ + kb + u * 64 + b0 * 8 + 32);
      }
    }
#pragma unroll
    for (int u = 0; u < 2; ++u) {  // 64-key subchunk
      const short* kbase = bufp + u * 4096;
      const short* vbase = bufp + 8192 + u * 4096;
      // ---- phase 1: QK for 4 key-tiles -> P fragments (exp2 domain) ----
      short4v pA[4], pB[4];
#pragma unroll
      for (int t = 0; t < 4; ++t) {
        const short8 ak0 = *(const short8*)(kbase + t * 1024 + ak0off);
        const short8 ak1 = *(const short8*)(kbase + t * 1024 + ak1off);
        float4v cA = zz, cB = zz;
        cA = mfma32(ak0, bqA0, cA);
        cA = mfma32(ak1, bqA1, cA);
        cB = mfma32(ak0, bqB0, cB);
        cB = mfma32(ak1, bqB1, cB);
        float eA[4], eB[4];
#pragma unroll
        for (int r = 0; r < 4; ++r) {
          eA[r] = __builtin_amdgcn_exp2f(cA[r]); lsA[r] += eA[r];
          eB[r] = __builtin_amdgcn_exp2f(cB[r]); lsB[r] += eB[r];
        }
        pA[t] = pk4(eA[0], eA[1], eA[2], eA[3]);
        pB[t] = pk4(eB[0], eB[1], eB[2], eB[3]);
      }
      // ---- phase 2: PV; 2x b128 per dt cover all 4 key-tiles (swizzled v) ----
#pragma unroll
      for (int dt = 0; dt < 4; ++dt) {
        const int rb = (dt * 16 + l15) * 64;
        const short8 av0 = *(const short8*)(vbase + rb + vb0off);
        const short8 av1 = *(const short8*)(vbase + rb + vb1off);
        const short4v a0 = {av0[0], av0[1], av0[2], av0[3]};
        const short4v a1 = {av0[4], av0[5], av0[6], av0[7]};
        const short4v a2 = {av1[0], av1[1], av1[2], av1[3]};
        const short4v a3 = {av1[4], av1[5], av1[6], av1[7]};
        oaccA[dt] = mfma16(a0, pA[0], oaccA[dt]);
        oaccB[dt] = mfma16(a0, pB[0], oaccB[dt]);
        oaccA[dt] = mfma16(a1, pA[1], oaccA[dt]);
        oaccB[dt] = mfma16(a1, pB[1], oaccB[dt]);
        oaccA[dt] = mfma16(a2, pA[2], oaccA[dt]);
        oaccB[dt] = mfma16(a2, pB[2], oaccB[dt]);
        oaccA[dt] = mfma16(a3, pA[3], oaccA[dt]);
        oaccB[dt] = mfma16(a3, pB[3], oaccB[dt]);
      }
    }
    p ^= 1;
  }
  // ---- epilogue: quad-reduce l; LDS transpose (b128, conflict-free) ----
  float lA = (lsA[0] + lsA[1]) + (lsA[2] + lsA[3]);
  float lB = (lsB[0] + lsB[1]) + (lsB[2] + lsB[3]);
  lA += __shfl_xor(lA, 16); lA += __shfl_xor(lA, 32);
  lB += __shfl_xor(lB, 16); lB += __shfl_xor(lB, 32);
  __syncthreads();
  float* mbuf = (float*)smem;            // [128][68]
  float* mlb = (float*)smem + 128 * 68;  // [128]
#pragma unroll
  for (int dt = 0; dt < 4; ++dt) {
    *(float4v*)&mbuf[qlA * 68 + dt * 16 + l4 * 4] = oaccA[dt];
    *(float4v*)&mbuf[qlB * 68 + dt * 16 + l4 * 4] = oaccB[dt];
  }
  if (l4 == 0) { mlb[qlA] = lA; mlb[qlB] = lB; }
  __syncthreads();
  const int qq = tid & 127;              // 64 consecutive lanes -> 64 rows
  const int dg = (tid >> 7) * 32;
  const float li = 1.f / mlb[qq];
  float* orow = out + (size_t)(b * S_ + q0 + qq) * D_ + h * HD_ + dg;
#pragma unroll
  for (int i = 0; i < 8; ++i) {
    float4v v = *(const float4v*)&mbuf[qq * 68 + dg + i * 4];
#pragma unroll
    for (int r = 0; r < 4; ++r) v[r] *= li;
    *(float4v*)(orow + i * 4) = v;
  }
}

extern "C" void kernel_launch(void* const* d_in, const int* in_sizes, int n_in,
                              void* d_out, int out_size, void* d_ws, size_t ws_size,
                              hipStream_t stream) {
  const float* hs = (const float*)d_in[0];
  const int* mask = (const int*)d_in[1];
  const float* Wq = (const float*)d_in[2];
  const float* bq = (const float*)d_in[3];
  const float* Wk = (const float*)d_in[4];
  const float* bk = (const float*)d_in[5];
  float* out = (float*)d_out;
  char* ws = (char*)d_ws;
  const size_t MB = 1u << 20;
  __hip_bfloat16* q_b = (__hip_bfloat16*)(ws + 0 * MB);   // [B,S,D] bf16, 8MB
  __hip_bfloat16* k_b = (__hip_bfloat16*)(ws + 8 * MB);   // softplus(k), 8MB
  __hip_bfloat16* vT  = (__hip_bfloat16*)(ws + 16 * MB);  // [B,H,HD,S] key-swizzled, 8MB
  __hip_bfloat16* Wqt = (__hip_bfloat16*)(ws + 24 * MB);  // 2MB
  __hip_bfloat16* Wkt = (__hip_bfloat16*)(ws + 26 * MB);  // 2MB
  __hip_bfloat16* hsb = (__hip_bfloat16*)(ws + 28 * MB);  // [B,S,D] bf16, 8MB

  prep<<<dim3(2560), 256, 0, stream>>>(hs, hsb, Wq, Wk, Wqt, Wkt);
  gemm_fused<<<dim3(512), 256, 0, stream>>>(hsb, Wqt, Wkt, bq, bk, q_b, k_b, vT);
  attn<<<dim3(512), 256, 0, stream>>>(q_b, k_b, vT, mask, out);
}

// Round 5
// 158.098 us; speedup vs baseline: 1.0134x; 1.0134x over previous
//
#include <hip/hip_runtime.h>
#include <hip/hip_bf16.h>

#define B_ 2
#define S_ 2048
#define D_ 1024
#define H_ 16
#define HD_ 64

typedef __attribute__((ext_vector_type(8))) short short8;
typedef __attribute__((ext_vector_type(4))) short short4v;
typedef __attribute__((ext_vector_type(4))) float float4v;

typedef const __attribute__((address_space(1))) void* gas_ptr;
typedef __attribute__((address_space(3))) void* las_ptr;

static __device__ inline void gl_lds16(const void* g, void* l) {
  __builtin_amdgcn_global_load_lds((gas_ptr)g, (las_ptr)l, 16, 0, 0);
}

static __device__ inline short f2bs(float x) {
  __hip_bfloat16 h = __float2bfloat16(x);
  union { __hip_bfloat16 h; short s; } u; u.h = h; return u.s;
}
static __device__ inline float bs2f(short s) {
  union { short s; __hip_bfloat16 h; } u; u.s = s; return __bfloat162float(u.h);
}
// packed f32x4 -> bf16x4 (v_cvt_pk_bf16_f32 x2)
static __device__ inline short4v pk4(float a, float b, float c, float d) {
  union { __hip_bfloat162 h[2]; short4v s; } u;
  u.h[0] = __float22bfloat162_rn(float2{a, b});
  u.h[1] = __float22bfloat162_rn(float2{c, d});
  return u.s;
}

static __device__ inline float4v mfma32(short8 a, short8 b, float4v c) {
  return __builtin_amdgcn_mfma_f32_16x16x32_bf16(a, b, c, 0, 0, 0);
}
// v_mfma_f32_16x16x16_bf16 — "_1k" builtin, present on gfx950.
static __device__ inline float4v mfma16(short4v a, short4v b, float4v c) {
  return __builtin_amdgcn_mfma_f32_16x16x16bf16_1k(a, b, c, 0, 0, 0);
}

// ------- Stage A (merged): blocks [0,2048): hs fp32->bf16; blocks [2048,2560):
// W fp32 [k][n] -> Wt bf16 [n][k]. -------
__global__ __launch_bounds__(256) void prep(
    const float* __restrict__ hs, __hip_bfloat16* __restrict__ hsb,
    const float* __restrict__ Wq, const float* __restrict__ Wk,
    __hip_bfloat16* __restrict__ Wqt, __hip_bfloat16* __restrict__ Wkt) {
  __shared__ float t[64][65];
  const int id = blockIdx.x;
  if (id < 2048) {
    const size_t i = ((size_t)id * 256 + threadIdx.x) * 8;
    const float4v a0 = ((const float4v*)(hs + i))[0];
    const float4v a1 = ((const float4v*)(hs + i))[1];
    short8 s;
#pragma unroll
    for (int j = 0; j < 4; ++j) { s[j] = f2bs(a0[j]); s[4 + j] = f2bs(a1[j]); }
    *(short8*)(hsb + i) = s;
    return;
  }
  const int bid = id - 2048;
  const float* W = (bid >> 8) ? Wk : Wq;
  __hip_bfloat16* Wt = (bid >> 8) ? Wkt : Wqt;
  const int n0 = (bid & 15) * 64, k0 = ((bid >> 4) & 15) * 64;
  const int c = threadIdx.x & 63, r0 = threadIdx.x >> 6;
  for (int i = 0; i < 16; ++i) {
    const int r = i * 4 + r0;
    t[c][r] = W[(size_t)(k0 + r) * D_ + n0 + c];
  }
  __syncthreads();
  for (int i = 0; i < 16; ++i) {
    const int rr = i * 4 + r0;
    Wt[(size_t)(n0 + rr) * D_ + k0 + c] = __float2bfloat16(t[rr][c]);
  }
}

// ---- Stage B (fused GEMM+prep): r18 version (BK=32; r19's BK=64 was -1.6us).
// 64x128 tile, 4 waves, 2 blocks/CU so the barrier drain of one block
// overlaps the other block's MFMA (m97/m114).
__global__ __launch_bounds__(256, 2) void gemm_fused(
    const __hip_bfloat16* __restrict__ hsb,
    const __hip_bfloat16* __restrict__ Wqt, const __hip_bfloat16* __restrict__ Wkt,
    const float* __restrict__ bq, const float* __restrict__ bk,
    __hip_bfloat16* __restrict__ q_out, __hip_bfloat16* __restrict__ kt_out,
    __hip_bfloat16* __restrict__ vT) {
  const int id = blockIdx.x;
  const int mt = (id & 7) * 8 + ((id >> 3) & 7);  // m-tile 0..63, pinned by xcd
  const int nt = id >> 6;                          // n-block 0..7
  const int n0 = nt * 128, m0 = mt * 64;
  __shared__ __hip_bfloat16 As[2][64 * 32];    // 8KB
  __shared__ __hip_bfloat16 Bq[2][128 * 32];   // 16KB
  __shared__ __hip_bfloat16 Bk[2][128 * 32];   // 16KB
  const int tid = threadIdx.x, wid = tid >> 6, lane = tid & 63;
  const int wm = (wid >> 1) * 32, wn = (wid & 1) * 64;
  const int l15 = lane & 15, l4 = lane >> 4;
  const float4v zz = {0.f, 0.f, 0.f, 0.f};
  float4v accq[2][4], acck[2][4];
  for (int i = 0; i < 2; ++i)
    for (int j = 0; j < 4; ++j) { accq[i][j] = zz; acck[i][j] = zz; }
  const int lrow = wid * 16 + (lane >> 2);
  const int lk8 = (((lane & 3) ^ ((lane >> 3) & 3)) * 8);
  // preload chunk 0: A 1 write, Bq 2 (rows 0-63, 64-127), Bk 2
  {
    gl_lds16(hsb + (size_t)(m0 + lrow) * D_ + lk8, As[0] + wid * 512);
    gl_lds16(Wqt + (size_t)(n0 + lrow) * D_ + lk8, Bq[0] + wid * 512);
    gl_lds16(Wqt + (size_t)(n0 + 64 + lrow) * D_ + lk8, Bq[0] + 2048 + wid * 512);
    gl_lds16(Wkt + (size_t)(n0 + lrow) * D_ + lk8, Bk[0] + wid * 512);
    gl_lds16(Wkt + (size_t)(n0 + 64 + lrow) * D_ + lk8, Bk[0] + 2048 + wid * 512);
  }
  int p = 0;
  for (int kb = 0; kb < 32; ++kb) {
    __syncthreads();  // buf[p] staged (vm drained); prev frag reads done
    if (kb < 31) {
      const int kc = (kb + 1) * 32 + lk8;
      gl_lds16(hsb + (size_t)(m0 + lrow) * D_ + kc, As[p ^ 1] + wid * 512);
      gl_lds16(Wqt + (size_t)(n0 + lrow) * D_ + kc, Bq[p ^ 1] + wid * 512);
      gl_lds16(Wqt + (size_t)(n0 + 64 + lrow) * D_ + kc, Bq[p ^ 1] + 2048 + wid * 512);
      gl_lds16(Wkt + (size_t)(n0 + lrow) * D_ + kc, Bk[p ^ 1] + wid * 512);
      gl_lds16(Wkt + (size_t)(n0 + 64 + lrow) * D_ + kc, Bk[p ^ 1] + 2048 + wid * 512);
    }
    short8 af[2], bfq[4], bfk[4];
    const int fo = ((l4 ^ ((l15 >> 1) & 3)) * 8);  // de-swizzle on read
    for (int rt = 0; rt < 2; ++rt)
      af[rt] = *(const short8*)(As[p] + (wm + rt * 16 + l15) * 32 + fo);
    for (int ct = 0; ct < 4; ++ct) {
      bfq[ct] = *(const short8*)(Bq[p] + (wn + ct * 16 + l15) * 32 + fo);
      bfk[ct] = *(const short8*)(Bk[p] + (wn + ct * 16 + l15) * 32 + fo);
    }
    for (int rt = 0; rt < 2; ++rt)
      for (int ct = 0; ct < 4; ++ct) {
        accq[rt][ct] = mfma32(af[rt], bfq[ct], accq[rt][ct]);
        acck[rt][ct] = mfma32(af[rt], bfk[ct], acck[rt][ct]);
      }
    p ^= 1;
  }
  float bvq[4], bvk[4];
  for (int ct = 0; ct < 4; ++ct) {
    bvq[ct] = bq[n0 + wn + ct * 16 + l15];
    bvk[ct] = bk[n0 + wn + ct * 16 + l15];
  }
  for (int rt = 0; rt < 2; ++rt)
    for (int ct = 0; ct < 4; ++ct) {
      const int col = n0 + wn + ct * 16 + l15;
      const int h = col >> 6, d = col & 63;
      const int rowb = m0 + wm + rt * 16 + l4 * 4;
      short4v vv;
      for (int r = 0; r < 4; ++r) {
        const int row = rowb + r;
        const float qv = accq[rt][ct][r] + bvq[ct];
        const float kv = acck[rt][ct][r] + bvk[ct];
        const float sp = fmaxf(kv, 0.f) + __logf(1.f + __expf(-fabsf(kv)));
        q_out[(size_t)row * D_ + col] = __float2bfloat16(qv);
        kt_out[(size_t)row * D_ + col] = __float2bfloat16(sp);
        vv[r] = f2bs(qv + kv);
      }
      const int b = rowb >> 11, s = rowb & 2047;
      // key swizzle p(k) within 64-chunk; s%4==0 -> 4 consecutive stay together
      const int sw = (s & ~63) | (((s >> 4) & 3) << 2) | (((s >> 2) & 3) << 4);
      *(short4v*)(vT + ((size_t)(b * H_ + h) * HD_ + d) * S_ + sw) = vv;
    }
}

// ------- Stage D: flash attention — XCD-pinned, 128-key chunks.
// r20 KEY-SPLIT: SQ_LDS_BANK_CONFLICT decoded as exactly 4x(ds_read_b128
// wave insts) — a per-inst structural constant, NOT fixable conflicts
// (r15-r19: bit-identical 4194304 across 3 different swizzle overhauls).
// Calibrated pipe model: LDS ~26us of the 55us wall — the dominant pipe.
// The 4x redundancy: each of 4 waves read the FULL 32KB K+V chunk.
// Fix: wave w = q-segment (w&1: 64 rows, 4 q-tiles) x key-half (w>>1).
// Per-wave LDS reads halve (16 b128/chunk); mfma/exp2/staging counts
// unchanged (no duplication). Partial O/lsum summed across key-halves in
// the epilogue (kh=0 writes mbuf, barrier, kh=1 adds).
__global__ __launch_bounds__(256, 2) void attn(
    const __hip_bfloat16* __restrict__ qb, const __hip_bfloat16* __restrict__ ktb,
    const __hip_bfloat16* __restrict__ vT, const int* __restrict__ mask,
    float* __restrict__ out) {
  // buffer: kt0[4096] kt1[4096] v0[4096] v1[4096] shorts; 2 bufs = 65536 B
  __shared__ short smem[32768];
  const int id = blockIdx.x;
  const int xcd = id & 7;
  const int rest = id >> 3;              // 0..63
  const int q0 = (rest & 15) * 128;      // q-tile
  const int hb = (rest >> 4) * 8 + xcd;  // 0..31
  const int h = hb >> 1, b = hb & 1;
  const int tid = threadIdx.x, wid = tid >> 6, lane = tid & 63;
  const int l15 = lane & 15, l4 = lane >> 4;
  const int qs = (wid & 1) * 64;         // q-segment (4 tiles of 16)
  const int kh = wid >> 1;               // key-half (64 keys of the 128-chunk)
  const __hip_bfloat16* qh = qb + (size_t)b * S_ * D_ + h * HD_;
  const __hip_bfloat16* kh_ = ktb + (size_t)b * S_ * D_ + h * HD_;
  const __hip_bfloat16* vh = vT + (size_t)(b * H_ + h) * HD_ * S_;
  // staging map (cooperative, tid-based, both halves): row=tid>>2, blocks b0,b0+4
  const int srow = tid >> 2;
  const int b0 = tid & 3;
  const int ssw = ((srow & 1) << 2) | ((srow >> 1) & 3);  // s(row)
  const int w0 = srow * 64 + ((b0 ^ ssw) * 8);
  const int w1 = srow * 64 + (((b0 + 4) ^ ssw) * 8);

  // Q B-fragments for the wave's 4 q-tiles; mask*scale*log2e folded in
  const float SC = 0.125f * 1.44269504f;
  short8 bq0[4], bq1[4];
#pragma unroll
  for (int T = 0; T < 4; ++T) {
    const int qr = q0 + qs + T * 16 + l15;
    const float mq = (mask[b * S_ + qr] != 0) ? SC : 0.f;
    const short8 r0 = *(const short8*)(qh + (size_t)qr * D_ + l4 * 8);
    const short8 r1 = *(const short8*)(qh + (size_t)qr * D_ + 32 + l4 * 8);
#pragma unroll
    for (int j = 0; j < 8; ++j) {
      bq0[T][j] = f2bs(bs2f(r0[j]) * mq);
      bq1[T][j] = f2bs(bs2f(r1[j]) * mq);
    }
  }

  // fragment read offsets (s(row)-swizzled; row&7 == l15&7 for all reads)
  const int lsw = ((l15 & 1) << 2) | ((l15 >> 1) & 3);
  const int ak0off = l15 * 64 + ((l4 ^ lsw) * 8);          // + kh*4096 + t*1024
  const int ak1off = l15 * 64 + (((l4 + 4) ^ lsw) * 8);
  const int vb0off = ((2 * l4) ^ lsw) * 8;                 // + 8192 + kh*4096 + row*64
  const int vb1off = ((2 * l4 + 1) ^ lsw) * 8;

  const float4v zz = {0.f, 0.f, 0.f, 0.f};
  float4v oacc[4][4];  // [T][dt]
#pragma unroll
  for (int T = 0; T < 4; ++T)
#pragma unroll
    for (int dt = 0; dt < 4; ++dt) oacc[T][dt] = zz;
  float4v ls[4] = {zz, zz, zz, zz};  // per-T, per-r partial sums

  // prefetch chunk 0 (two 64-key subchunks, cooperative)
  short8 gk0[2], gk1[2], gv0[2], gv1[2];
#pragma unroll
  for (int u = 0; u < 2; ++u) {
    gk0[u] = *(const short8*)(kh_ + (size_t)(u * 64 + srow) * D_ + b0 * 8);
    gk1[u] = *(const short8*)(kh_ + (size_t)(u * 64 + srow) * D_ + b0 * 8 + 32);
    gv0[u] = *(const short8*)(vh + (size_t)srow * S_ + u * 64 + b0 * 8);
    gv1[u] = *(const short8*)(vh + (size_t)srow * S_ + u * 64 + b0 * 8 + 32);
  }

  int pb = 0;
  for (int c = 0; c < 16; ++c) {
    short* bufp = smem + pb * 16384;
#pragma unroll
    for (int u = 0; u < 2; ++u) {
      *(short8*)(bufp + u * 4096 + w0) = gk0[u];
      *(short8*)(bufp + u * 4096 + w1) = gk1[u];
      *(short8*)(bufp + 8192 + u * 4096 + w0) = gv0[u];
      *(short8*)(bufp + 8192 + u * 4096 + w1) = gv1[u];
    }
    __syncthreads();
    if (c < 15) {
      const int kb = (c + 1) * 128;
#pragma unroll
      for (int u = 0; u < 2; ++u) {
        gk0[u] = *(const short8*)(kh_ + (size_t)(kb + u * 64 + srow) * D_ + b0 * 8);
        gk1[u] = *(const short8*)(kh_ + (size_t)(kb + u * 64 + srow) * D_ + b0 * 8 + 32);
        gv0[u] = *(const short8*)(vh + (size_t)srow * S_ + kb + u * 64 + b0 * 8);
        gv1[u] = *(const short8*)(vh + (size_t)srow * S_ + kb + u * 64 + b0 * 8 + 32);
      }
    }
    const short* kbase = bufp + kh * 4096;           // this wave's key-half
    const short* vbase = bufp + 8192 + kh * 4096;
    // ---- phase 1: QK, 4 key-tiles x 4 q-tiles -> P fragments (exp2 domain)
    short4v pf[4][4];  // [T][t]
#pragma unroll
    for (int t = 0; t < 4; ++t) {
      const short8 ak0 = *(const short8*)(kbase + t * 1024 + ak0off);
      const short8 ak1 = *(const short8*)(kbase + t * 1024 + ak1off);
#pragma unroll
      for (int T = 0; T < 4; ++T) {
        float4v cc = zz;
        cc = mfma32(ak0, bq0[T], cc);
        cc = mfma32(ak1, bq1[T], cc);
        float e[4];
#pragma unroll
        for (int r = 0; r < 4; ++r) {
          e[r] = __builtin_amdgcn_exp2f(cc[r]); ls[T][r] += e[r];
        }
        pf[T][t] = pk4(e[0], e[1], e[2], e[3]);
      }
    }
    // ---- phase 2: PV over the wave's 64 keys ----
#pragma unroll
    for (int dt = 0; dt < 4; ++dt) {
      const int rb = (dt * 16 + l15) * 64;
      const short8 av0 = *(const short8*)(vbase + rb + vb0off);
      const short8 av1 = *(const short8*)(vbase + rb + vb1off);
      const short4v a0 = {av0[0], av0[1], av0[2], av0[3]};
      const short4v a1 = {av0[4], av0[5], av0[6], av0[7]};
      const short4v a2 = {av1[0], av1[1], av1[2], av1[3]};
      const short4v a3 = {av1[4], av1[5], av1[6], av1[7]};
#pragma unroll
      for (int T = 0; T < 4; ++T) {
        oacc[T][dt] = mfma16(a0, pf[T][0], oacc[T][dt]);
        oacc[T][dt] = mfma16(a1, pf[T][1], oacc[T][dt]);
        oacc[T][dt] = mfma16(a2, pf[T][2], oacc[T][dt]);
        oacc[T][dt] = mfma16(a3, pf[T][3], oacc[T][dt]);
      }
    }
    pb ^= 1;
  }
  // ---- epilogue: reduce l per tile; combine key-halves; normalize ----
  float lT[4];
#pragma unroll
  for (int T = 0; T < 4; ++T) {
    lT[T] = (ls[T][0] + ls[T][1]) + (ls[T][2] + ls[T][3]);
    lT[T] += __shfl_xor(lT[T], 16);
    lT[T] += __shfl_xor(lT[T], 32);
  }
  __syncthreads();
  float* mbuf = (float*)smem;            // [128][68]
  float* mlb = (float*)smem + 128 * 68;  // [128]
  if (kh == 0) {
#pragma unroll
    for (int T = 0; T < 4; ++T) {
      const int row = qs + T * 16 + l15;
#pragma unroll
      for (int dt = 0; dt < 4; ++dt)
        *(float4v*)&mbuf[row * 68 + dt * 16 + l4 * 4] = oacc[T][dt];
      if (l4 == 0) mlb[row] = lT[T];
    }
  }
  __syncthreads();
  if (kh == 1) {
#pragma unroll
    for (int T = 0; T < 4; ++T) {
      const int row = qs + T * 16 + l15;
#pragma unroll
      for (int dt = 0; dt < 4; ++dt) {
        float4v v = *(const float4v*)&mbuf[row * 68 + dt * 16 + l4 * 4];
        v += oacc[T][dt];
        *(float4v*)&mbuf[row * 68 + dt * 16 + l4 * 4] = v;
      }
      if (l4 == 0) mlb[row] += lT[T];
    }
  }
  __syncthreads();
  const int qq = tid & 127;              // 64 consecutive lanes -> 64 rows
  const int dg = (tid >> 7) * 32;
  const float li = 1.f / mlb[qq];
  float* orow = out + (size_t)(b * S_ + q0 + qq) * D_ + h * HD_ + dg;
#pragma unroll
  for (int i = 0; i < 8; ++i) {
    float4v v = *(const float4v*)&mbuf[qq * 68 + dg + i * 4];
#pragma unroll
    for (int r = 0; r < 4; ++r) v[r] *= li;
    *(float4v*)(orow + i * 4) = v;
  }
}

extern "C" void kernel_launch(void* const* d_in, const int* in_sizes, int n_in,
                              void* d_out, int out_size, void* d_ws, size_t ws_size,
                              hipStream_t stream) {
  const float* hs = (const float*)d_in[0];
  const int* mask = (const int*)d_in[1];
  const float* Wq = (const float*)d_in[2];
  const float* bq = (const float*)d_in[3];
  const float* Wk = (const float*)d_in[4];
  const float* bk = (const float*)d_in[5];
  float* out = (float*)d_out;
  char* ws = (char*)d_ws;
  const size_t MB = 1u << 20;
  __hip_bfloat16* q_b = (__hip_bfloat16*)(ws + 0 * MB);   // [B,S,D] bf16, 8MB
  __hip_bfloat16* k_b = (__hip_bfloat16*)(ws + 8 * MB);   // softplus(k), 8MB
  __hip_bfloat16* vT  = (__hip_bfloat16*)(ws + 16 * MB);  // [B,H,HD,S] key-swizzled, 8MB
  __hip_bfloat16* Wqt = (__hip_bfloat16*)(ws + 24 * MB);  // 2MB
  __hip_bfloat16* Wkt = (__hip_bfloat16*)(ws + 26 * MB);  // 2MB
  __hip_bfloat16* hsb = (__hip_bfloat16*)(ws + 28 * MB);  // [B,S,D] bf16, 8MB

  prep<<<dim3(2560), 256, 0, stream>>>(hs, hsb, Wq, Wk, Wqt, Wkt);
  gemm_fused<<<dim3(512), 256, 0, stream>>>(hsb, Wqt, Wkt, bq, bk, q_b, k_b, vT);
  attn<<<dim3(512), 256, 0, stream>>>(q_b, k_b, vT, mask, out);
}